// Round 11
// baseline (140.143 us; speedup 1.0000x reference)
//
#include <hip/hip_runtime.h>
#include <hip/hip_bf16.h>

#define BATCH   4
#define NBOX    8192
#define BLOCK   256
#define TSZ     256                  // tile size (rows & cols)
#define NT      (NBOX / TSZ)         // 32 tiles per batch
#define NPAIRS  (NT * (NT + 1) / 2)  // 528 tile-pairs per batch
#define NBINS   2048

__device__ __forceinline__ float bf2f(unsigned short u) {
    union { unsigned int i; float f; } c;
    c.i = ((unsigned int)u) << 16;
    return c.f;
}

__device__ __forceinline__ bool box_plausible(float x1, float y1, float x2, float y2) {
    bool ok = (x1 == x1) && (y1 == y1) && (x2 == x2) && (y2 == y2);
    ok = ok && fabsf(x1) < 1e4f && fabsf(y1) < 1e4f && fabsf(x2) < 1e4f && fabsf(y2) < 1e4f;
    ok = ok && x1 >= -1.0f && x1 <= 300.0f && y1 >= -1.0f && y1 <= 300.0f;
    const float w = x2 - x1, h = y2 - y1;
    ok = ok && w >= -0.1f && w <= 80.0f && h >= -0.1f && h <= 80.0f;
    return ok;
}

// Wave-redundant dtype probe; all waves deterministically agree. true -> f32.
__device__ __forceinline__ bool wave_probe_is_f32(const void* boxes_raw) {
    const int lane = threadIdx.x & 63;
    const float* bf = (const float*)boxes_raw;
    const bool okf = box_plausible(bf[lane * 4 + 0], bf[lane * 4 + 1],
                                   bf[lane * 4 + 2], bf[lane * 4 + 3]);
    const unsigned short* bh = (const unsigned short*)boxes_raw;
    const bool okh = box_plausible(bf2f(bh[lane * 4 + 0]), bf2f(bh[lane * 4 + 1]),
                                   bf2f(bh[lane * 4 + 2]), bf2f(bh[lane * 4 + 3]));
    const unsigned long long mf = __ballot(okf);
    const unsigned long long mh = __ballot(okh);
    return __popcll(mf) >= __popcll(mh);
}

__device__ __forceinline__ float4 load_box(const void* boxes_raw, size_t idx, bool isf32) {
    if (isf32) {
        return reinterpret_cast<const float4*>(boxes_raw)[idx];
    } else {
        const ushort4 u = reinterpret_cast<const ushort4*>(boxes_raw)[idx];
        return make_float4(bf2f(u.x), bf2f(u.y), bf2f(u.z), bf2f(u.w));
    }
}

__device__ __forceinline__ float load_score(const void* scores_raw, size_t idx, bool isf32) {
    return isf32 ? ((const float*)scores_raw)[idx]
                 : bf2f(((const unsigned short*)scores_raw)[idx]);
}

// exp(-iou/0.5) = exp2(iou * (-2 log2 e)); arg in [-2.886, 0] -> raw v_exp ok
#define CEXP (-2.8853900817779268f)

__device__ __forceinline__ float pair_weight(
    float ix1, float iy1, float ix2, float iy2, float iarea,
    const float4& bj, float jarea)
{
    float w = fminf(ix2, bj.z) - fmaxf(ix1, bj.x);
    float h = fminf(iy2, bj.w) - fmaxf(iy1, bj.y);
    w = fmaxf(w, 0.0f);
    h = fmaxf(h, 0.0f);
    const float inter = w * h;
    const float uni   = iarea + jarea - inter;          // >= ~1 always
    const float arg   = (CEXP * inter) * __builtin_amdgcn_rcpf(uni);
    return __builtin_amdgcn_exp2f(arg);
}

// Kernel 0: per-batch counting sort by x1 (2048 bins) into f32 arrays in ws;
// also zeroes adj. One block per batch. Sorting enables x-interval tile-pair
// culling: non-intersecting tile-pairs have inter==0 -> weight==1 exactly,
// handled as a per-tile score-sum correction in the finish kernel.
__global__ __launch_bounds__(1024) void sort_kernel(
    const void* __restrict__ boxes_raw, const void* __restrict__ scores_raw,
    float4* __restrict__ sboxes, float* __restrict__ sscores,
    float* __restrict__ adj)
{
    __shared__ int hist[NBINS];
    __shared__ int wsum[1024];

    const int b   = blockIdx.x;
    const int tid = threadIdx.x;
    const bool isf32 = wave_probe_is_f32(boxes_raw);
    const size_t base = (size_t)b * NBOX;

    for (int i = tid; i < NBINS; i += 1024) hist[i] = 0;
#pragma unroll
    for (int k = 0; k < NBOX / 1024; k++) adj[base + k * 1024 + tid] = 0.0f;
    __syncthreads();

    // load 8 boxes/thread, histogram by x1
    float4 bx[8]; float sc[8]; int bin[8];
#pragma unroll
    for (int k = 0; k < 8; k++) {
        const int i = k * 1024 + tid;
        bx[k] = load_box(boxes_raw, base + i, isf32);
        sc[k] = load_score(scores_raw, base + i, isf32);
        int bb = (int)(bx[k].x * ((float)NBINS / 256.0f));
        bin[k] = min(NBINS - 1, max(0, bb));
        atomicAdd(&hist[bin[k]], 1);
    }
    __syncthreads();

    // exclusive scan over 2048 bins (2 bins/thread + Hillis-Steele on 1024)
    const int h0 = hist[2 * tid], h1 = hist[2 * tid + 1];
    const int s  = h0 + h1;
    wsum[tid] = s;
    __syncthreads();
    for (int off = 1; off < 1024; off <<= 1) {
        const int v = (tid >= off) ? wsum[tid - off] : 0;
        __syncthreads();
        wsum[tid] += v;
        __syncthreads();
    }
    const int ex = wsum[tid] - s;
    hist[2 * tid]     = ex;          // all hist reads happened before the scan
    hist[2 * tid + 1] = ex + h0;
    __syncthreads();

    // scatter
#pragma unroll
    for (int k = 0; k < 8; k++) {
        const int pos = atomicAdd(&hist[bin[k]], 1);
        sboxes[base + pos]  = bx[k];
        sscores[base + pos] = sc[k];
    }
}

// Kernel 1: adjusted[b][i] = sum_j w_ij * s_j over INTERSECTING tile-pairs
// (round-7 hot loop). Non-intersecting pairs are skipped after an exact
// min/max meta check (bitwise-consistent with finish's check).
__global__ __launch_bounds__(BLOCK, 4) void soft_nms_adj_kernel(
    const float4* __restrict__ sboxes,   // (B,N) sorted f32 boxes
    const float* __restrict__ sscores,   // (B,N) sorted f32 scores
    float* __restrict__ adj)             // (B,N) f32, zeroed
{
    __shared__ float4 sbox[TSZ];          // j-tile: x1,y1,x2,y2
    __shared__ float2 sas[TSZ];           // j-tile: area, score
    __shared__ float  srow[4][TSZ];       // per-wave row partials
    __shared__ float  red[4][4];          // meta partials: jmin,jmax,imin,imax

    const int bid = blockIdx.x;
    const int b   = bid / NPAIRS;
    int p = bid % NPAIRS;
    int it = 0;
    while (p >= NT - it) { p -= NT - it; it++; }   // triangular decode
    const int jt = it + p;

    const int tid  = threadIdx.x;
    const int lane = tid & 63;
    const int wv   = tid >> 6;
    const size_t base = (size_t)b * NBOX;

    // stage j-tile into LDS
    float jmin, jmax;
    {
        const int jg = jt * TSZ + tid;
        const float4 uj = sboxes[base + jg];
        sbox[tid] = uj;
        sas[tid]  = make_float2((uj.z - uj.x) * (uj.w - uj.y), sscores[base + jg]);
        jmin = uj.x; jmax = uj.z;
    }

    // rows: thread owns rows {k*64 + lane} of the i-tile (same set in every wave)
    float rx1[4], ry1[4], rx2[4], ry2[4], rar[4], rsc[4], accr[4];
#pragma unroll
    for (int k = 0; k < 4; k++) {
        const int ig = it * TSZ + k * 64 + lane;
        const float4 ui = sboxes[base + ig];
        rx1[k] = ui.x; ry1[k] = ui.y; rx2[k] = ui.z; ry2[k] = ui.w;
        rar[k] = (ui.z - ui.x) * (ui.w - ui.y);
        rsc[k] = sscores[base + ig];
        accr[k] = 0.0f;
    }

    // block meta: min x1 / max x2 for both tiles (exact, order-independent)
    float imin = fminf(fminf(rx1[0], rx1[1]), fminf(rx1[2], rx1[3]));
    float imax = fmaxf(fmaxf(rx2[0], rx2[1]), fmaxf(rx2[2], rx2[3]));
#pragma unroll
    for (int off = 32; off > 0; off >>= 1) {
        jmin = fminf(jmin, __shfl_down(jmin, off));
        jmax = fmaxf(jmax, __shfl_down(jmax, off));
        imin = fminf(imin, __shfl_down(imin, off));
        imax = fmaxf(imax, __shfl_down(imax, off));
    }
    if (lane == 0) {
        red[wv][0] = jmin; red[wv][1] = jmax; red[wv][2] = imin; red[wv][3] = imax;
    }
    __syncthreads();
    jmin = fminf(fminf(red[0][0], red[1][0]), fminf(red[2][0], red[3][0]));
    jmax = fmaxf(fmaxf(red[0][1], red[1][1]), fmaxf(red[2][1], red[3][1]));
    imin = fminf(fminf(red[0][2], red[1][2]), fminf(red[2][2], red[3][2]));
    imax = fmaxf(fmaxf(red[0][3], red[1][3]), fmaxf(red[2][3], red[3][3]));

    // x-intervals disjoint -> every cross pair has inter==0 (weight==1),
    // handled by finish's ssum correction. Uniform branch.
    if ((imax < jmin) || (jmax < imin)) return;

    const int wvbase = wv * 64;

    if (it == jt) {
        // diagonal: full ordered pairs, row side only (includes i==j)
#pragma unroll 2
        for (int t = 0; t < 64; t++) {
            const int idx = wvbase + ((lane + t) & 63);
            const float4 bj = sbox[idx];
            const float2 as = sas[idx];
#pragma unroll
            for (int k = 0; k < 4; k++) {
                const float e = pair_weight(rx1[k], ry1[k], rx2[k], ry2[k], rar[k], bj, as.x);
                accr[k] = fmaf(e, as.y, accr[k]);
            }
        }
    } else {
        // off-diagonal: symmetric; col accumulator rides in registers per lane
        float accc = 0.0f;
#pragma unroll 2
        for (int t = 0; t < 64; t++) {
            const int idx = wvbase + ((lane + t) & 63);
            const float4 bj = sbox[idx];       // stride-1 window: conflict-free
            const float2 as = sas[idx];
            const float e0 = pair_weight(rx1[0], ry1[0], rx2[0], ry2[0], rar[0], bj, as.x);
            const float e1 = pair_weight(rx1[1], ry1[1], rx2[1], ry2[1], rar[1], bj, as.x);
            const float e2 = pair_weight(rx1[2], ry1[2], rx2[2], ry2[2], rar[2], bj, as.x);
            const float e3 = pair_weight(rx1[3], ry1[3], rx2[3], ry2[3], rar[3], bj, as.x);
            accr[0] = fmaf(e0, as.y, accr[0]);
            accr[1] = fmaf(e1, as.y, accr[1]);
            accr[2] = fmaf(e2, as.y, accr[2]);
            accr[3] = fmaf(e3, as.y, accr[3]);
            const float c = fmaf(e0, rsc[0], fmaf(e1, rsc[1], fmaf(e2, rsc[2], e3 * rsc[3])));
            accc += __shfl(c, (lane - t) & 63);    // owner lane (lane+t)&63 pulls
        }
        atomicAdd(&adj[base + jt * TSZ + wvbase + lane], accc);  // exclusive window
    }

    // combine row partials across the 4 waves via LDS, one atomic per row
#pragma unroll
    for (int k = 0; k < 4; k++) srow[wv][k * 64 + lane] = accr[k];
    __syncthreads();
    {
        const float rs = srow[0][tid] + srow[1][tid] + srow[2][tid] + srow[3][tid];
        atomicAdd(&adj[base + it * TSZ + tid], rs);
    }
}

// Kernel 2: per batch: tile meta + skipped-pair ssum correction, then
// softmax(adjusted) and weighted sum of boxes -> 4 outputs.
#define FBLK 1024
__global__ __launch_bounds__(FBLK) void soft_nms_finish_kernel(
    const float4* __restrict__ sboxes,   // (B,N) sorted f32 boxes
    const float* __restrict__ sscores,   // (B,N) sorted f32 scores
    const float* __restrict__ adj,       // (B,N) f32
    const void* __restrict__ boxes_raw,  // only for output-dtype probe
    void* __restrict__ out)              // (B,4) dtype matches input
{
    constexpr int K  = NBOX / FBLK;             // 8 items per thread
    constexpr int NW = FBLK / 64;               // 16 waves
    __shared__ float sminx[NT], smaxx[NT], ssumT[NT], scorr[NT];
    __shared__ float smax_[NW];
    __shared__ float sred[NW][5];

    const int b    = blockIdx.x;
    const int tid  = threadIdx.x;
    const int lane = tid & 63;
    const int wv   = tid >> 6;
    const size_t base = (size_t)b * NBOX;

    const bool isf32 = wave_probe_is_f32(boxes_raw);

    // tile meta: wave wv covers tiles 2wv, 2wv+1 (min/max exact + score sum)
#pragma unroll
    for (int tt = 0; tt < 2; tt++) {
        const int T = wv * 2 + tt;
        float mn = 1e30f, mx = -1e30f, sm = 0.0f;
#pragma unroll
        for (int q = 0; q < 4; q++) {
            const int i = T * TSZ + q * 64 + lane;
            const float4 u = sboxes[base + i];
            mn = fminf(mn, u.x);
            mx = fmaxf(mx, u.z);
            sm += sscores[base + i];
        }
#pragma unroll
        for (int off = 32; off > 0; off >>= 1) {
            mn = fminf(mn, __shfl_down(mn, off));
            mx = fmaxf(mx, __shfl_down(mx, off));
            sm += __shfl_down(sm, off);
        }
        if (lane == 0) { sminx[T] = mn; smaxx[T] = mx; ssumT[T] = sm; }
    }
    __syncthreads();
    if (tid < NT) {
        float c = 0.0f;
        for (int T2 = 0; T2 < NT; T2++) {
            const bool skip = (smaxx[tid] < sminx[T2]) || (smaxx[T2] < sminx[tid]);
            if (skip) c += ssumT[T2];
        }
        scorr[tid] = c;
    }
    __syncthreads();

    float av[K];
    float m = -3.4e38f;
#pragma unroll
    for (int k = 0; k < K; k++) {
        const int r = k * FBLK + tid;
        av[k] = adj[base + r] + scorr[r >> 8];
        m = fmaxf(m, av[k]);
    }
#pragma unroll
    for (int off = 32; off > 0; off >>= 1)
        m = fmaxf(m, __shfl_down(m, off));
    if (lane == 0) smax_[wv] = m;
    __syncthreads();
    float M = smax_[0];
#pragma unroll
    for (int w = 1; w < NW; w++) M = fmaxf(M, smax_[w]);

    const float L2E = 1.4426950408889634f;
    float es = 0.0f, s0 = 0.0f, s1 = 0.0f, s2 = 0.0f, s3 = 0.0f;
#pragma unroll
    for (int k = 0; k < K; k++) {
        const float e = __builtin_amdgcn_exp2f((av[k] - M) * L2E);
        const float4 u = sboxes[base + k * FBLK + tid];
        es += e;
        s0 += e * u.x;
        s1 += e * u.y;
        s2 += e * u.z;
        s3 += e * u.w;
    }
#pragma unroll
    for (int off = 32; off > 0; off >>= 1) {
        es += __shfl_down(es, off);
        s0 += __shfl_down(s0, off);
        s1 += __shfl_down(s1, off);
        s2 += __shfl_down(s2, off);
        s3 += __shfl_down(s3, off);
    }
    if (lane == 0) {
        sred[wv][0] = es; sred[wv][1] = s0; sred[wv][2] = s1;
        sred[wv][3] = s2; sred[wv][4] = s3;
    }
    __syncthreads();
    if (tid == 0) {
        float ES = 0.0f, o[4] = {0.0f, 0.0f, 0.0f, 0.0f};
#pragma unroll
        for (int w = 0; w < NW; w++) {
            ES   += sred[w][0];
            o[0] += sred[w][1];
            o[1] += sred[w][2];
            o[2] += sred[w][3];
            o[3] += sred[w][4];
        }
        const float inv = 1.0f / ES;
        if (isf32) {
            float* of = (float*)out;
            for (int c = 0; c < 4; c++) of[b * 4 + c] = o[c] * inv;
        } else {
            __hip_bfloat16* oh = (__hip_bfloat16*)out;
            for (int c = 0; c < 4; c++) oh[b * 4 + c] = __float2bfloat16(o[c] * inv);
        }
    }
}

extern "C" void kernel_launch(void* const* d_in, const int* in_sizes, int n_in,
                              void* d_out, int out_size, void* d_ws, size_t ws_size,
                              hipStream_t stream) {
    const void* boxes_raw  = d_in[0];   // (4,8192,4)
    const void* scores_raw = d_in[1];   // (4,8192)

    float4* sboxes  = (float4*)d_ws;                                // 512 KB
    float*  sscores = (float*)(sboxes + (size_t)BATCH * NBOX);      // 128 KB
    float*  adj     = sscores + (size_t)BATCH * NBOX;               // 128 KB

    sort_kernel<<<dim3(BATCH), dim3(1024), 0, stream>>>(
        boxes_raw, scores_raw, sboxes, sscores, adj);
    soft_nms_adj_kernel<<<dim3(BATCH * NPAIRS), dim3(BLOCK), 0, stream>>>(
        sboxes, sscores, adj);
    soft_nms_finish_kernel<<<dim3(BATCH), dim3(FBLK), 0, stream>>>(
        sboxes, sscores, adj, boxes_raw, d_out);
}

// Round 12
// 121.750 us; speedup vs baseline: 1.1511x; 1.1511x over previous
//
#include <hip/hip_runtime.h>
#include <hip/hip_bf16.h>

#define BATCH   4
#define NBOX    8192
#define BLOCK   256
#define TSZ     256                  // tile size (rows & cols)
#define NT      (NBOX / TSZ)         // 32 tiles per batch
#define NPAIRS  (NT * (NT + 1) / 2)  // 528 tile-pairs per batch
#define NBINS   2048

__device__ __forceinline__ float bf2f(unsigned short u) {
    union { unsigned int i; float f; } c;
    c.i = ((unsigned int)u) << 16;
    return c.f;
}

__device__ __forceinline__ bool box_plausible(float x1, float y1, float x2, float y2) {
    bool ok = (x1 == x1) && (y1 == y1) && (x2 == x2) && (y2 == y2);
    ok = ok && fabsf(x1) < 1e4f && fabsf(y1) < 1e4f && fabsf(x2) < 1e4f && fabsf(y2) < 1e4f;
    ok = ok && x1 >= -1.0f && x1 <= 300.0f && y1 >= -1.0f && y1 <= 300.0f;
    const float w = x2 - x1, h = y2 - y1;
    ok = ok && w >= -0.1f && w <= 80.0f && h >= -0.1f && h <= 80.0f;
    return ok;
}

// Wave-redundant dtype probe; all waves deterministically agree. true -> f32.
__device__ __forceinline__ bool wave_probe_is_f32(const void* boxes_raw) {
    const int lane = threadIdx.x & 63;
    const float* bf = (const float*)boxes_raw;
    const bool okf = box_plausible(bf[lane * 4 + 0], bf[lane * 4 + 1],
                                   bf[lane * 4 + 2], bf[lane * 4 + 3]);
    const unsigned short* bh = (const unsigned short*)boxes_raw;
    const bool okh = box_plausible(bf2f(bh[lane * 4 + 0]), bf2f(bh[lane * 4 + 1]),
                                   bf2f(bh[lane * 4 + 2]), bf2f(bh[lane * 4 + 3]));
    const unsigned long long mf = __ballot(okf);
    const unsigned long long mh = __ballot(okh);
    return __popcll(mf) >= __popcll(mh);
}

__device__ __forceinline__ float4 load_box(const void* boxes_raw, size_t idx, bool isf32) {
    if (isf32) {
        return reinterpret_cast<const float4*>(boxes_raw)[idx];
    } else {
        const ushort4 u = reinterpret_cast<const ushort4*>(boxes_raw)[idx];
        return make_float4(bf2f(u.x), bf2f(u.y), bf2f(u.z), bf2f(u.w));
    }
}

__device__ __forceinline__ float load_score(const void* scores_raw, size_t idx, bool isf32) {
    return isf32 ? ((const float*)scores_raw)[idx]
                 : bf2f(((const unsigned short*)scores_raw)[idx]);
}

// exp(-iou/0.5) = exp2(iou * (-2 log2 e)); arg in [-2.886, 0] -> raw v_exp ok
#define CEXP (-2.8853900817779268f)

__device__ __forceinline__ float pair_weight(
    float ix1, float iy1, float ix2, float iy2, float iarea,
    const float4& bj, float jarea)
{
    float w = fminf(ix2, bj.z) - fmaxf(ix1, bj.x);
    float h = fminf(iy2, bj.w) - fmaxf(iy1, bj.y);
    w = fmaxf(w, 0.0f);
    h = fmaxf(h, 0.0f);
    const float inter = w * h;
    const float uni   = iarea + jarea - inter;          // >= ~1 always
    const float arg   = (CEXP * inter) * __builtin_amdgcn_rcpf(uni);
    return __builtin_amdgcn_exp2f(arg);
}

// Kernel 0: per-batch counting sort by x1 (2048 bins); zeroes adj; computes
// per-tile x meta (LDS int atomics: valid since coords >= 0 -> float bits
// monotone) and the live tile-pair list. 3 barriers total in the scan
// (round-11's Hillis-Steele used 20 -> dominated the kernel).
__global__ __launch_bounds__(1024) void sort_kernel(
    const void* __restrict__ boxes_raw, const void* __restrict__ scores_raw,
    float4* __restrict__ sboxes, float* __restrict__ sscores,
    float* __restrict__ adj,
    float* __restrict__ minxg, float* __restrict__ maxxg,   // (B,NT)
    int* __restrict__ pairlist, int* __restrict__ count)    // (B,NPAIRS), (B)
{
    __shared__ int hist[NBINS];
    __shared__ int wtot[16];
    __shared__ int iminx[NT], imaxx[NT];
    __shared__ int scnt;

    const int b    = blockIdx.x;
    const int tid  = threadIdx.x;
    const int lane = tid & 63;
    const int wv   = tid >> 6;
    const bool isf32 = wave_probe_is_f32(boxes_raw);
    const size_t base = (size_t)b * NBOX;

    hist[2 * tid]     = 0;
    hist[2 * tid + 1] = 0;
    if (tid < NT) { iminx[tid] = 0x7f800000; imaxx[tid] = 0; }
    if (tid == 0) scnt = 0;
#pragma unroll
    for (int k = 0; k < NBOX / 1024; k++) adj[base + k * 1024 + tid] = 0.0f;
    __syncthreads();

    // load 8 boxes/thread, histogram by x1
    float4 bx[8]; float sc[8]; int bin[8];
#pragma unroll
    for (int k = 0; k < 8; k++) {
        const int i = k * 1024 + tid;
        bx[k] = load_box(boxes_raw, base + i, isf32);
        sc[k] = load_score(scores_raw, base + i, isf32);
        int bb = (int)(bx[k].x * ((float)NBINS / 256.0f));
        bin[k] = min(NBINS - 1, max(0, bb));
        atomicAdd(&hist[bin[k]], 1);
    }
    __syncthreads();

    // exclusive scan over 2048 bins: 2 bins/thread, wave shfl scan + 16-wave scan
    const int h0 = hist[2 * tid], h1 = hist[2 * tid + 1];
    const int s  = h0 + h1;
    int v = s;                       // wave-inclusive scan
#pragma unroll
    for (int d = 1; d < 64; d <<= 1) {
        const int u = __shfl_up(v, d);
        if (lane >= d) v += u;
    }
    if (lane == 63) wtot[wv] = v;
    __syncthreads();
    if (wv == 0 && lane < 16) {      // scan the 16 wave totals (inclusive)
        int w = wtot[lane];
#pragma unroll
        for (int d = 1; d < 16; d <<= 1) {
            const int u = __shfl_up(w, d);
            if (lane >= d) w += u;
        }
        wtot[lane] = w;
    }
    __syncthreads();
    const int ex = (wv > 0 ? wtot[wv - 1] : 0) + (v - s);
    hist[2 * tid]     = ex;          // each thread touches only its own 2 bins
    hist[2 * tid + 1] = ex + h0;
    __syncthreads();

    // scatter + per-tile x meta
#pragma unroll
    for (int k = 0; k < 8; k++) {
        const int pos = atomicAdd(&hist[bin[k]], 1);
        sboxes[base + pos]  = bx[k];
        sscores[base + pos] = sc[k];
        const int T = pos >> 8;
        atomicMin(&iminx[T], __float_as_int(bx[k].x));
        atomicMax(&imaxx[T], __float_as_int(bx[k].z));
    }
    __syncthreads();

    // publish meta + build live pair list (same compares finish will use)
    if (tid < NT) {
        minxg[b * NT + tid] = __int_as_float(iminx[tid]);
        maxxg[b * NT + tid] = __int_as_float(imaxx[tid]);
    }
    if (tid < NPAIRS) {
        int p = tid, it = 0;
        while (p >= NT - it) { p -= NT - it; it++; }
        const int jt = it + p;
        const float mi = __int_as_float(iminx[it]), Mi = __int_as_float(imaxx[it]);
        const float mj = __int_as_float(iminx[jt]), Mj = __int_as_float(imaxx[jt]);
        const bool live = !((Mi < mj) || (Mj < mi));
        if (live) {
            const int idx = atomicAdd(&scnt, 1);
            pairlist[b * NPAIRS + idx] = (it << 8) | jt;
        }
    }
    __syncthreads();
    if (tid == 0) count[b] = scnt;
}

// Kernel 1: adjusted over live tile-pairs only (round-7 hot loop). Dead
// blocks exit after two scalar loads; no in-kernel meta check.
__global__ __launch_bounds__(BLOCK, 4) void soft_nms_adj_kernel(
    const float4* __restrict__ sboxes,   // (B,N) sorted f32 boxes
    const float* __restrict__ sscores,   // (B,N) sorted f32 scores
    const int* __restrict__ pairlist,    // (B,NPAIRS) live pairs
    const int* __restrict__ count,       // (B)
    float* __restrict__ adj)             // (B,N) f32, zeroed
{
    __shared__ float4 sbox[TSZ];          // j-tile: x1,y1,x2,y2
    __shared__ float2 sas[TSZ];           // j-tile: area, score
    __shared__ float  srow[4][TSZ];       // per-wave row partials

    const int bid = blockIdx.x;
    const int b   = bid / NPAIRS;
    const int p   = bid % NPAIRS;
    if (p >= count[b]) return;            // dead block: ~2 scalar loads
    const int pr = pairlist[b * NPAIRS + p];
    const int it = pr >> 8, jt = pr & 255;

    const int tid  = threadIdx.x;
    const int lane = tid & 63;
    const int wv   = tid >> 6;
    const size_t base = (size_t)b * NBOX;

    // stage j-tile into LDS
    {
        const int jg = jt * TSZ + tid;
        const float4 uj = sboxes[base + jg];
        sbox[tid] = uj;
        sas[tid]  = make_float2((uj.z - uj.x) * (uj.w - uj.y), sscores[base + jg]);
    }

    // rows: thread owns rows {k*64 + lane} of the i-tile (same set in every wave)
    float rx1[4], ry1[4], rx2[4], ry2[4], rar[4], rsc[4], accr[4];
#pragma unroll
    for (int k = 0; k < 4; k++) {
        const int ig = it * TSZ + k * 64 + lane;
        const float4 ui = sboxes[base + ig];
        rx1[k] = ui.x; ry1[k] = ui.y; rx2[k] = ui.z; ry2[k] = ui.w;
        rar[k] = (ui.z - ui.x) * (ui.w - ui.y);
        rsc[k] = sscores[base + ig];
        accr[k] = 0.0f;
    }

    __syncthreads();

    const int wvbase = wv * 64;

    if (it == jt) {
        // diagonal: full ordered pairs, row side only (includes i==j)
#pragma unroll 2
        for (int t = 0; t < 64; t++) {
            const int idx = wvbase + ((lane + t) & 63);
            const float4 bj = sbox[idx];
            const float2 as = sas[idx];
#pragma unroll
            for (int k = 0; k < 4; k++) {
                const float e = pair_weight(rx1[k], ry1[k], rx2[k], ry2[k], rar[k], bj, as.x);
                accr[k] = fmaf(e, as.y, accr[k]);
            }
        }
    } else {
        // off-diagonal: symmetric; col accumulator rides in registers per lane
        float accc = 0.0f;
#pragma unroll 2
        for (int t = 0; t < 64; t++) {
            const int idx = wvbase + ((lane + t) & 63);
            const float4 bj = sbox[idx];       // stride-1 window: conflict-free
            const float2 as = sas[idx];
            const float e0 = pair_weight(rx1[0], ry1[0], rx2[0], ry2[0], rar[0], bj, as.x);
            const float e1 = pair_weight(rx1[1], ry1[1], rx2[1], ry2[1], rar[1], bj, as.x);
            const float e2 = pair_weight(rx1[2], ry1[2], rx2[2], ry2[2], rar[2], bj, as.x);
            const float e3 = pair_weight(rx1[3], ry1[3], rx2[3], ry2[3], rar[3], bj, as.x);
            accr[0] = fmaf(e0, as.y, accr[0]);
            accr[1] = fmaf(e1, as.y, accr[1]);
            accr[2] = fmaf(e2, as.y, accr[2]);
            accr[3] = fmaf(e3, as.y, accr[3]);
            const float c = fmaf(e0, rsc[0], fmaf(e1, rsc[1], fmaf(e2, rsc[2], e3 * rsc[3])));
            accc += __shfl(c, (lane - t) & 63);    // owner lane (lane+t)&63 pulls
        }
        atomicAdd(&adj[base + jt * TSZ + wvbase + lane], accc);  // exclusive window
    }

    // combine row partials across the 4 waves via LDS, one atomic per row
#pragma unroll
    for (int k = 0; k < 4; k++) srow[wv][k * 64 + lane] = accr[k];
    __syncthreads();
    {
        const float rs = srow[0][tid] + srow[1][tid] + srow[2][tid] + srow[3][tid];
        atomicAdd(&adj[base + it * TSZ + tid], rs);
    }
}

// Kernel 2: per batch: skipped-pair ssum correction (from the SAME meta the
// list builder used), then softmax(adjusted) + weighted box sum -> 4 outputs.
#define FBLK 1024
__global__ __launch_bounds__(FBLK) void soft_nms_finish_kernel(
    const float4* __restrict__ sboxes,   // (B,N) sorted f32 boxes
    const float* __restrict__ sscores,   // (B,N) sorted f32 scores
    const float* __restrict__ adj,       // (B,N) f32
    const float* __restrict__ minxg, const float* __restrict__ maxxg,  // (B,NT)
    const void* __restrict__ boxes_raw,  // only for output-dtype probe
    void* __restrict__ out)              // (B,4) dtype matches input
{
    constexpr int K  = NBOX / FBLK;             // 8 items per thread
    constexpr int NW = FBLK / 64;               // 16 waves
    __shared__ float sminx[NT], smaxx[NT], ssumT[NT], scorr[NT];
    __shared__ float smax_[NW];
    __shared__ float sred[NW][5];

    const int b    = blockIdx.x;
    const int tid  = threadIdx.x;
    const int lane = tid & 63;
    const int wv   = tid >> 6;
    const size_t base = (size_t)b * NBOX;

    const bool isf32 = wave_probe_is_f32(boxes_raw);

    if (tid < NT) {
        sminx[tid] = minxg[b * NT + tid];
        smaxx[tid] = maxxg[b * NT + tid];
    }
    // per-tile score sums: wave wv covers tiles 2wv, 2wv+1
#pragma unroll
    for (int tt = 0; tt < 2; tt++) {
        const int T = wv * 2 + tt;
        float sm = 0.0f;
#pragma unroll
        for (int q = 0; q < 4; q++) sm += sscores[base + T * TSZ + q * 64 + lane];
#pragma unroll
        for (int off = 32; off > 0; off >>= 1) sm += __shfl_down(sm, off);
        if (lane == 0) ssumT[T] = sm;
    }
    __syncthreads();
    if (tid < NT) {
        float c = 0.0f;
        for (int T2 = 0; T2 < NT; T2++) {
            const bool skip = (smaxx[tid] < sminx[T2]) || (smaxx[T2] < sminx[tid]);
            if (skip) c += ssumT[T2];
        }
        scorr[tid] = c;
    }
    __syncthreads();

    float av[K];
    float m = -3.4e38f;
#pragma unroll
    for (int k = 0; k < K; k++) {
        const int r = k * FBLK + tid;
        av[k] = adj[base + r] + scorr[r >> 8];
        m = fmaxf(m, av[k]);
    }
#pragma unroll
    for (int off = 32; off > 0; off >>= 1)
        m = fmaxf(m, __shfl_down(m, off));
    if (lane == 0) smax_[wv] = m;
    __syncthreads();
    float M = smax_[0];
#pragma unroll
    for (int w = 1; w < NW; w++) M = fmaxf(M, smax_[w]);

    const float L2E = 1.4426950408889634f;
    float es = 0.0f, s0 = 0.0f, s1 = 0.0f, s2 = 0.0f, s3 = 0.0f;
#pragma unroll
    for (int k = 0; k < K; k++) {
        const float e = __builtin_amdgcn_exp2f((av[k] - M) * L2E);
        const float4 u = sboxes[base + k * FBLK + tid];
        es += e;
        s0 += e * u.x;
        s1 += e * u.y;
        s2 += e * u.z;
        s3 += e * u.w;
    }
#pragma unroll
    for (int off = 32; off > 0; off >>= 1) {
        es += __shfl_down(es, off);
        s0 += __shfl_down(s0, off);
        s1 += __shfl_down(s1, off);
        s2 += __shfl_down(s2, off);
        s3 += __shfl_down(s3, off);
    }
    if (lane == 0) {
        sred[wv][0] = es; sred[wv][1] = s0; sred[wv][2] = s1;
        sred[wv][3] = s2; sred[wv][4] = s3;
    }
    __syncthreads();
    if (tid == 0) {
        float ES = 0.0f, o[4] = {0.0f, 0.0f, 0.0f, 0.0f};
#pragma unroll
        for (int w = 0; w < NW; w++) {
            ES   += sred[w][0];
            o[0] += sred[w][1];
            o[1] += sred[w][2];
            o[2] += sred[w][3];
            o[3] += sred[w][4];
        }
        const float inv = 1.0f / ES;
        if (isf32) {
            float* of = (float*)out;
            for (int c = 0; c < 4; c++) of[b * 4 + c] = o[c] * inv;
        } else {
            __hip_bfloat16* oh = (__hip_bfloat16*)out;
            for (int c = 0; c < 4; c++) oh[b * 4 + c] = __float2bfloat16(o[c] * inv);
        }
    }
}

extern "C" void kernel_launch(void* const* d_in, const int* in_sizes, int n_in,
                              void* d_out, int out_size, void* d_ws, size_t ws_size,
                              hipStream_t stream) {
    const void* boxes_raw  = d_in[0];   // (4,8192,4)
    const void* scores_raw = d_in[1];   // (4,8192)

    char* w = (char*)d_ws;
    float4* sboxes   = (float4*)w;                     w += (size_t)BATCH * NBOX * 16;
    float*  sscores  = (float*)w;                      w += (size_t)BATCH * NBOX * 4;
    float*  adj      = (float*)w;                      w += (size_t)BATCH * NBOX * 4;
    float*  minxg    = (float*)w;                      w += (size_t)BATCH * NT * 4;
    float*  maxxg    = (float*)w;                      w += (size_t)BATCH * NT * 4;
    int*    pairlist = (int*)w;                        w += (size_t)BATCH * NPAIRS * 4;
    int*    count    = (int*)w;

    sort_kernel<<<dim3(BATCH), dim3(1024), 0, stream>>>(
        boxes_raw, scores_raw, sboxes, sscores, adj, minxg, maxxg, pairlist, count);
    soft_nms_adj_kernel<<<dim3(BATCH * NPAIRS), dim3(BLOCK), 0, stream>>>(
        sboxes, sscores, pairlist, count, adj);
    soft_nms_finish_kernel<<<dim3(BATCH), dim3(FBLK), 0, stream>>>(
        sboxes, sscores, adj, minxg, maxxg, boxes_raw, d_out);
}